// Round 8
// baseline (288.829 us; speedup 1.0000x reference)
//
#include <hip/hip_runtime.h>
#include <math.h>

#define HEADS 8
#define KNB 32
#define CIN 128
#define COUT 256
#define BB 4
#define NN 8192
#define EPSV 1e-5f
#define SLOPE 0.2f

typedef _Float16 h8 __attribute__((ext_vector_type(8)));
typedef _Float16 h4 __attribute__((ext_vector_type(4)));
typedef float f4 __attribute__((ext_vector_type(4)));

// ---------------- QKV GEMM (fp16 MFMA) ----------------
// x: [B][CIN][N] fp32, W: [COUT][CIN] fp32 -> Q/K/V fp16 node-major [B][N][COUT].
// grid 6144, XCD-affinity decode: 12 (mat,co) tiles of one (b,ntile) per XCD.
// Block 0 also zeroes the BN partial-sum accumulators (consumed by wo_kernel).
__global__ __launch_bounds__(256) void qkv_kernel(
    const float* __restrict__ x,
    const float* __restrict__ Wq, const float* __restrict__ Wk, const float* __restrict__ Wv,
    _Float16* __restrict__ Q, _Float16* __restrict__ K, _Float16* __restrict__ V,
    float* __restrict__ pz)
{
    __shared__ _Float16 wl[16][65][8];  // [k/8][co(+pad)][k%8]
    __shared__ _Float16 xl[16][65][8];  // [k/8][n (+pad)][k%8]
    const int t = threadIdx.x;
    if (blockIdx.x == 0) { pz[t] = 0.f; pz[t + 256] = 0.f; }  // ps, pss
    const int i = blockIdx.x;
    const int xcd = i & 7;
    const int local = i >> 3;
    const int matco = local % 12;
    const int tl = local / 12;
    const int g = tl * 8 + xcd;
    const int b = g >> 7;
    const int n0 = (g & 127) << 6;
    const int mat = matco >> 2;
    const int co0 = (matco & 3) << 6;
    const float* __restrict__ W = (mat == 0) ? Wq : (mat == 1) ? Wk : Wv;

    // stage W tile 64co x 128k (fp32 -> fp16), h4 writes
#pragma unroll
    for (int it = 0; it < 8; ++it) {
        const int flat = t + it * 256;
        const int co = flat >> 5;
        const int k4 = (flat & 31) << 2;
        float4 wv = *(const float4*)(W + (size_t)(co0 + co) * CIN + k4);
        h4 hv; hv[0] = (_Float16)wv.x; hv[1] = (_Float16)wv.y;
        hv[2] = (_Float16)wv.z; hv[3] = (_Float16)wv.w;
        *(h4*)&wl[k4 >> 3][co][k4 & 7] = hv;
    }
    // stage x tile 128k x 64n: 4-k packed h4 writes (transpose in registers)
#pragma unroll
    for (int it = 0; it < 2; ++it) {
        const int flat = t + it * 256;          // 512 items = 32 ci-quads x 16 n-quads
        const int ci = (flat >> 4) << 2;        // 0..124 step 4
        const int n4 = (flat & 15) << 2;
        const f4 x0 = *(const f4*)(x + ((size_t)b * CIN + ci + 0) * NN + n0 + n4);
        const f4 x1 = *(const f4*)(x + ((size_t)b * CIN + ci + 1) * NN + n0 + n4);
        const f4 x2 = *(const f4*)(x + ((size_t)b * CIN + ci + 2) * NN + n0 + n4);
        const f4 x3 = *(const f4*)(x + ((size_t)b * CIN + ci + 3) * NN + n0 + n4);
#pragma unroll
        for (int j = 0; j < 4; ++j) {
            h4 hv; hv[0] = (_Float16)x0[j]; hv[1] = (_Float16)x1[j];
            hv[2] = (_Float16)x2[j]; hv[3] = (_Float16)x3[j];
            *(h4*)&xl[ci >> 3][n4 + j][ci & 7] = hv;
        }
    }
    __syncthreads();

    const int w = t >> 6, lane = t & 63;
    const int m = lane & 15, ko = lane >> 4;
    f4 acc[4];
#pragma unroll
    for (int j = 0; j < 4; ++j) acc[j] = (f4){0.f, 0.f, 0.f, 0.f};
#pragma unroll
    for (int s = 0; s < 4; ++s) {
        const h8 a = *(const h8*)&wl[s * 4 + ko][w * 16 + m][0];
#pragma unroll
        for (int j = 0; j < 4; ++j) {
            const h8 bb = *(const h8*)&xl[s * 4 + ko][j * 16 + m][0];
            acc[j] = __builtin_amdgcn_mfma_f32_16x16x32_f16(a, bb, acc[j], 0, 0, 0);
        }
    }

    _Float16* __restrict__ Y = (mat == 0) ? Q : (mat == 1) ? K : V;
    const int cob = co0 + w * 16 + ko * 4;   // D: row=(lane>>4)*4+r, col=lane&15
#pragma unroll
    for (int j = 0; j < 4; ++j) {
        const int n = n0 + j * 16 + m;
        h4 hv; hv[0] = (_Float16)acc[j][0]; hv[1] = (_Float16)acc[j][1];
        hv[2] = (_Float16)acc[j][2]; hv[3] = (_Float16)acc[j][3];
        *(h4*)(Y + ((size_t)b * NN + n) * COUT + cob) = hv;
    }
}

// ---------------- Attention pass 1: scores + softmax -> weights fp16 ----------------
// Random universe per batch = K only = 4 MB = one XCD L2. Streaming (Q, edges,
// weights) is nt-hinted so K keeps the L2.
__global__ __launch_bounds__(256) void attn_scores(
    const _Float16* __restrict__ Q, const _Float16* __restrict__ K,
    const int* __restrict__ edges, _Float16* __restrict__ wbuf)
{
    __shared__ float s_sc[4][HEADS][33];
    __shared__ int s_idx[4][KNB];
    const int t = threadIdx.x;
    const int wv = t >> 6;
    const int lane = t & 63;
    const int b = blockIdx.y;
    const int n = (blockIdx.x << 2) + wv;
    const int h = lane >> 3;
    const int dg = lane & 7;
    const size_t nb = (size_t)b * NN;
    const size_t base = (nb + n) * COUT;
    const int c = lane * 4;

    const h4 qh = __builtin_nontemporal_load((const h4*)(Q + base + c));
    const float scl = 0.17677669529663688f;  // 1/sqrt(32)
    const float qx = (float)qh[0] * scl, qy = (float)qh[1] * scl;
    const float qz = (float)qh[2] * scl, qw = (float)qh[3] * scl;
    if (lane < KNB) s_idx[wv][lane] = __builtin_nontemporal_load(edges + (nb + n) * KNB + lane);
    __syncthreads();

    const _Float16* __restrict__ Kp = K + nb * COUT;
#pragma unroll
    for (int j = 0; j < KNB; ++j) {
        const h4 kh = *(const h4*)(Kp + (size_t)s_idx[wv][j] * COUT + c);
        float p = qx * (float)kh[0] + qy * (float)kh[1] + qz * (float)kh[2] + qw * (float)kh[3];
        p += __shfl_xor(p, 1, 8);
        p += __shfl_xor(p, 2, 8);
        p += __shfl_xor(p, 4, 8);
        if (dg == 0) s_sc[wv][h][j] = p;
    }
    __syncthreads();

    // softmax over 32 per head; write weights straight to global (coalesced 128B)
#pragma unroll
    for (int g = 0; g < 4; ++g) {
        const int id = g * 64 + lane;
        const int hh = id >> 5, jj = id & 31;
        float val = s_sc[wv][hh][jj];
        float mx = val;
        mx = fmaxf(mx, __shfl_xor(mx, 16, 32));
        mx = fmaxf(mx, __shfl_xor(mx, 8, 32));
        mx = fmaxf(mx, __shfl_xor(mx, 4, 32));
        mx = fmaxf(mx, __shfl_xor(mx, 2, 32));
        mx = fmaxf(mx, __shfl_xor(mx, 1, 32));
        float e = __expf(val - mx);
        float s = e;
        s += __shfl_xor(s, 16, 32);
        s += __shfl_xor(s, 8, 32);
        s += __shfl_xor(s, 4, 32);
        s += __shfl_xor(s, 2, 32);
        s += __shfl_xor(s, 1, 32);
        __builtin_nontemporal_store((_Float16)(e / s), wbuf + base + id);
    }
}

// ---------------- Attention pass 2: PV gather ----------------
__global__ __launch_bounds__(256) void attn_pv(
    const _Float16* __restrict__ V, const _Float16* __restrict__ wbuf,
    const int* __restrict__ edges, _Float16* __restrict__ feat)
{
    __shared__ float s_w[4][HEADS][33];
    __shared__ int s_idx[4][KNB];
    const int t = threadIdx.x;
    const int wv = t >> 6;
    const int lane = t & 63;
    const int b = blockIdx.y;
    const int n = (blockIdx.x << 2) + wv;
    const int h = lane >> 3;
    const size_t nb = (size_t)b * NN;
    const size_t base = (nb + n) * COUT;
    const int c = lane * 4;

    if (lane < KNB) s_idx[wv][lane] = __builtin_nontemporal_load(edges + (nb + n) * KNB + lane);
    {   // load this node's 256 weights: lane -> ids lane*4..lane*4+3
        const h4 wh = __builtin_nontemporal_load((const h4*)(wbuf + base + c));
        const int hh = lane >> 3;              // (lane*4)>>5
        const int jj = (lane * 4) & 31;
        s_w[wv][hh][jj + 0] = (float)wh[0];
        s_w[wv][hh][jj + 1] = (float)wh[1];
        s_w[wv][hh][jj + 2] = (float)wh[2];
        s_w[wv][hh][jj + 3] = (float)wh[3];
    }
    __syncthreads();

    const _Float16* __restrict__ Vp = V + nb * COUT;
    float ax = 0.f, ay = 0.f, az = 0.f, aw = 0.f;
#pragma unroll
    for (int j = 0; j < KNB; ++j) {
        const float w = s_w[wv][h][j];
        const h4 vh = *(const h4*)(Vp + (size_t)s_idx[wv][j] * COUT + c);
        ax += w * (float)vh[0]; ay += w * (float)vh[1];
        az += w * (float)vh[2]; aw += w * (float)vh[3];
    }
    h4 f; f[0] = (_Float16)ax; f[1] = (_Float16)ay; f[2] = (_Float16)az; f[3] = (_Float16)aw;
    __builtin_nontemporal_store(f, (h4*)(feat + base + c));  // feat aliases Q
}

// ---------------- Wo GEMM (fp16 MFMA) + fused BN partial sums ----------------
__global__ __launch_bounds__(256) void wo_kernel(
    const _Float16* __restrict__ feat, const float* __restrict__ Wo, float* __restrict__ o,
    float* __restrict__ ps, float* __restrict__ pss)
{
    __shared__ _Float16 wl[16][65][8];
    __shared__ _Float16 fl[16][65][8];
    const int t = threadIdx.x;
    const int i = blockIdx.x;
    const int xcd = i & 7;
    const int local = i >> 3;
    const int co0 = (local & 3) << 6;
    const int tl = local >> 2;
    const int g = tl * 8 + xcd;
    const int b = g >> 7;
    const int n0 = (g & 127) << 6;
    const int w = t >> 6, lane = t & 63;
    const int m = lane & 15, ko = lane >> 4;
    f4 acc[4];
#pragma unroll
    for (int j = 0; j < 4; ++j) acc[j] = (f4){0.f, 0.f, 0.f, 0.f};

    for (int c0 = 0; c0 < COUT; c0 += 128) {
#pragma unroll
        for (int it = 0; it < 8; ++it) {
            const int flat = t + it * 256;
            const int co = flat >> 5;
            const int k4 = (flat & 31) << 2;
            float4 wv = *(const float4*)(Wo + (size_t)(co0 + co) * COUT + c0 + k4);
            h4 hv; hv[0] = (_Float16)wv.x; hv[1] = (_Float16)wv.y;
            hv[2] = (_Float16)wv.z; hv[3] = (_Float16)wv.w;
            *(h4*)&wl[k4 >> 3][co][k4 & 7] = hv;
        }
#pragma unroll
        for (int it = 0; it < 4; ++it) {
            const int flat = t + it * 256;   // 1024 h8s = 64n x 16 c8
            const int n = flat >> 4;
            const int c8 = flat & 15;
            const h8 fv = *(const h8*)(feat + ((size_t)b * NN + n0 + n) * COUT + c0 + c8 * 8);
            *(h8*)&fl[c8][n][0] = fv;
        }
        __syncthreads();
#pragma unroll
        for (int s = 0; s < 4; ++s) {
            const h8 a = *(const h8*)&wl[s * 4 + ko][w * 16 + m][0];
#pragma unroll
            for (int j = 0; j < 4; ++j) {
                const h8 bb = *(const h8*)&fl[s * 4 + ko][j * 16 + m][0];
                acc[j] = __builtin_amdgcn_mfma_f32_16x16x32_f16(a, bb, acc[j], 0, 0, 0);
            }
        }
        __syncthreads();
    }

    const int cob = co0 + w * 16 + ko * 4;
#pragma unroll
    for (int j = 0; j < 4; ++j) {
        const int n = n0 + j * 16 + m;
        *(f4*)(o + ((size_t)b * NN + n) * COUT + cob) = acc[j];
    }

    // fused BN partials: this block covers 64 n's for co0..co0+63
    float s_[4], ss_[4];
#pragma unroll
    for (int r = 0; r < 4; ++r) {
        float sv = acc[0][r] + acc[1][r] + acc[2][r] + acc[3][r];
        float qv = acc[0][r] * acc[0][r] + acc[1][r] * acc[1][r]
                 + acc[2][r] * acc[2][r] + acc[3][r] * acc[3][r];
#pragma unroll
        for (int d = 1; d < 16; d <<= 1) {
            sv += __shfl_xor(sv, d, 16);
            qv += __shfl_xor(qv, d, 16);
        }
        s_[r] = sv; ss_[r] = qv;
    }
    if (m == 0) {
#pragma unroll
        for (int r = 0; r < 4; ++r) {
            atomicAdd(&ps[cob + r], s_[r]);
            atomicAdd(&pss[cob + r], ss_[r]);
        }
    }
}

// ---------------- BN apply + LeakyReLU + transpose to [b][co][n] ----------------
__global__ __launch_bounds__(256) void bn_apply(const float* __restrict__ o,
    const float* __restrict__ ps, const float* __restrict__ pss,
    const float* __restrict__ gamma, const float* __restrict__ beta,
    float* __restrict__ out)
{
    __shared__ float tile[64][68];
    __shared__ float s_sc[64], s_sh[64];
    const int i = blockIdx.x;           // 2048 = 4b x 4cotile x 128 ntile
    const int nt_ = i & 127, ct = (i >> 7) & 3, b = i >> 9;
    const int n0 = nt_ << 6, co0 = ct << 6;
    const int t = threadIdx.x;
    if (t < 64) {
        const int co = co0 + t;
        const float inv = 1.f / (float)(BB * NN);
        const float mean = ps[co] * inv;
        const float var = pss[co] * inv - mean * mean;
        const float istd = rsqrtf(var + EPSV);
        const float sc = gamma[co] * istd;
        s_sc[t] = sc;
        s_sh[t] = beta[co] - mean * sc;
    }
    const int cq = (t & 15) << 2, rg = t >> 4;
#pragma unroll
    for (int it = 0; it < 4; ++it) {
        const int n = rg + it * 16;
        f4 v = *(const f4*)(o + ((size_t)b * NN + n0 + n) * COUT + co0 + cq);
        *(f4*)&tile[n][cq] = v;
    }
    __syncthreads();
    const int n4 = (t & 15) << 2, cg = t >> 4;
#pragma unroll
    for (int it = 0; it < 4; ++it) {
        const int co = cg + it * 16;
        const float sc = s_sc[co];
        const float sh = s_sh[co];
        f4 r;
#pragma unroll
        for (int j = 0; j < 4; ++j) {
            float v = sc * tile[n4 + j][co] + sh;
            r[j] = (v >= 0.f) ? v : SLOPE * v;
        }
        *(f4*)(out + ((size_t)b * COUT + co0 + co) * NN + n0 + n4) = r;
    }
}

extern "C" void kernel_launch(void* const* d_in, const int* in_sizes, int n_in,
                              void* d_out, int out_size, void* d_ws, size_t ws_size,
                              hipStream_t stream)
{
    const float* x     = (const float*)d_in[0];
    const int*   edges = (const int*)d_in[1];
    const float* Wq    = (const float*)d_in[2];
    const float* Wk    = (const float*)d_in[3];
    const float* Wv    = (const float*)d_in[4];
    const float* Wo    = (const float*)d_in[5];
    const float* gamma = (const float*)d_in[6];
    const float* beta  = (const float*)d_in[7];
    float* out = (float*)d_out;

    const size_t SZ = (size_t)BB * NN * COUT;      // 8,388,608 elements
    _Float16* Q    = (_Float16*)d_ws;              // fp16
    _Float16* K    = Q + SZ;
    _Float16* V    = K + SZ;
    _Float16* wbuf = V + SZ;                       // fp16 softmax weights
    float*    o    = (float*)(wbuf + SZ);          // fp32 node-major
    float*    ps   = o + SZ;                       // 256
    float*    pss  = ps + COUT;                    // 256
    _Float16* feat = Q;                            // alias: per-node exclusive

    qkv_kernel<<<dim3(12 * 128 * BB), 256, 0, stream>>>(x, Wq, Wk, Wv, Q, K, V, ps);
    attn_scores<<<dim3(NN / 4, BB), 256, 0, stream>>>(Q, K, edges, wbuf);
    attn_pv<<<dim3(NN / 4, BB), 256, 0, stream>>>(V, wbuf, edges, feat);
    wo_kernel<<<dim3(4 * 128 * BB), 256, 0, stream>>>(feat, Wo, o, ps, pss);
    bn_apply<<<dim3(2048), 256, 0, stream>>>(o, ps, pss, gamma, beta, out);
}

// Round 9
// 281.738 us; speedup vs baseline: 1.0252x; 1.0252x over previous
//
#include <hip/hip_runtime.h>
#include <math.h>

#define HEADS 8
#define KNB 32
#define CIN 128
#define COUT 256
#define BB 4
#define NN 8192
#define EPSV 1e-5f
#define SLOPE 0.2f

typedef _Float16 h8 __attribute__((ext_vector_type(8)));
typedef _Float16 h4 __attribute__((ext_vector_type(4)));
typedef float f4 __attribute__((ext_vector_type(4)));

// ---------------- QKV GEMM (fp16 MFMA) ----------------
__global__ __launch_bounds__(256) void qkv_kernel(
    const float* __restrict__ x,
    const float* __restrict__ Wq, const float* __restrict__ Wk, const float* __restrict__ Wv,
    _Float16* __restrict__ Q, _Float16* __restrict__ K, _Float16* __restrict__ V,
    float* __restrict__ pz)
{
    __shared__ _Float16 wl[16][65][8];  // [k/8][co(+pad)][k%8]
    __shared__ _Float16 xl[16][65][8];  // [k/8][n (+pad)][k%8]
    const int t = threadIdx.x;
    if (blockIdx.x == 0) { pz[t] = 0.f; pz[t + 256] = 0.f; }  // ps, pss
    const int i = blockIdx.x;
    const int xcd = i & 7;
    const int local = i >> 3;
    const int matco = local % 12;
    const int tl = local / 12;
    const int g = tl * 8 + xcd;
    const int b = g >> 7;
    const int n0 = (g & 127) << 6;
    const int mat = matco >> 2;
    const int co0 = (matco & 3) << 6;
    const float* __restrict__ W = (mat == 0) ? Wq : (mat == 1) ? Wk : Wv;

#pragma unroll
    for (int it = 0; it < 8; ++it) {
        const int flat = t + it * 256;
        const int co = flat >> 5;
        const int k4 = (flat & 31) << 2;
        float4 wv = *(const float4*)(W + (size_t)(co0 + co) * CIN + k4);
        h4 hv; hv[0] = (_Float16)wv.x; hv[1] = (_Float16)wv.y;
        hv[2] = (_Float16)wv.z; hv[3] = (_Float16)wv.w;
        *(h4*)&wl[k4 >> 3][co][k4 & 7] = hv;
    }
#pragma unroll
    for (int it = 0; it < 2; ++it) {
        const int flat = t + it * 256;
        const int ci = (flat >> 4) << 2;
        const int n4 = (flat & 15) << 2;
        const f4 x0 = *(const f4*)(x + ((size_t)b * CIN + ci + 0) * NN + n0 + n4);
        const f4 x1 = *(const f4*)(x + ((size_t)b * CIN + ci + 1) * NN + n0 + n4);
        const f4 x2 = *(const f4*)(x + ((size_t)b * CIN + ci + 2) * NN + n0 + n4);
        const f4 x3 = *(const f4*)(x + ((size_t)b * CIN + ci + 3) * NN + n0 + n4);
#pragma unroll
        for (int j = 0; j < 4; ++j) {
            h4 hv; hv[0] = (_Float16)x0[j]; hv[1] = (_Float16)x1[j];
            hv[2] = (_Float16)x2[j]; hv[3] = (_Float16)x3[j];
            *(h4*)&xl[ci >> 3][n4 + j][ci & 7] = hv;
        }
    }
    __syncthreads();

    const int w = t >> 6, lane = t & 63;
    const int m = lane & 15, ko = lane >> 4;
    f4 acc[4];
#pragma unroll
    for (int j = 0; j < 4; ++j) acc[j] = (f4){0.f, 0.f, 0.f, 0.f};
#pragma unroll
    for (int s = 0; s < 4; ++s) {
        const h8 a = *(const h8*)&wl[s * 4 + ko][w * 16 + m][0];
#pragma unroll
        for (int j = 0; j < 4; ++j) {
            const h8 bb = *(const h8*)&xl[s * 4 + ko][j * 16 + m][0];
            acc[j] = __builtin_amdgcn_mfma_f32_16x16x32_f16(a, bb, acc[j], 0, 0, 0);
        }
    }

    _Float16* __restrict__ Y = (mat == 0) ? Q : (mat == 1) ? K : V;
    const int cob = co0 + w * 16 + ko * 4;
#pragma unroll
    for (int j = 0; j < 4; ++j) {
        const int n = n0 + j * 16 + m;
        h4 hv; hv[0] = (_Float16)acc[j][0]; hv[1] = (_Float16)acc[j][1];
        hv[2] = (_Float16)acc[j][2]; hv[3] = (_Float16)acc[j][3];
        *(h4*)(Y + ((size_t)b * NN + n) * COUT + cob) = hv;
    }
}

// ---------------- Attention pass 1: scores + softmax -> weights fp16 ----------------
// All 32 K-row gathers issued into registers back-to-back (32-deep MLP), then
// the dot/reduce. Random universe per batch = K = 4 MB = one XCD L2.
__global__ __launch_bounds__(256) void attn_scores(
    const _Float16* __restrict__ Q, const _Float16* __restrict__ K,
    const int* __restrict__ edges, _Float16* __restrict__ wbuf)
{
    __shared__ float s_sc[4][HEADS][33];
    __shared__ int s_idx[4][KNB];
    const int t = threadIdx.x;
    const int wv = t >> 6;
    const int lane = t & 63;
    const int b = blockIdx.y;
    const int n = (blockIdx.x << 2) + wv;
    const int h = lane >> 3;
    const int dg = lane & 7;
    const size_t nb = (size_t)b * NN;
    const size_t base = (nb + n) * COUT;
    const int c = lane * 4;

    const h4 qh = __builtin_nontemporal_load((const h4*)(Q + base + c));
    const float scl = 0.17677669529663688f;  // 1/sqrt(32)
    const float qx = (float)qh[0] * scl, qy = (float)qh[1] * scl;
    const float qz = (float)qh[2] * scl, qw = (float)qh[3] * scl;
    if (lane < KNB) s_idx[wv][lane] = __builtin_nontemporal_load(edges + (nb + n) * KNB + lane);
    __syncthreads();

    const _Float16* __restrict__ Kp = K + nb * COUT;
    h4 kreg[KNB];
#pragma unroll
    for (int j = 0; j < KNB; ++j)
        kreg[j] = *(const h4*)(Kp + (size_t)s_idx[wv][j] * COUT + c);

#pragma unroll
    for (int j = 0; j < KNB; ++j) {
        float p = qx * (float)kreg[j][0] + qy * (float)kreg[j][1]
                + qz * (float)kreg[j][2] + qw * (float)kreg[j][3];
        p += __shfl_xor(p, 1, 8);
        p += __shfl_xor(p, 2, 8);
        p += __shfl_xor(p, 4, 8);
        if (dg == 0) s_sc[wv][h][j] = p;
    }
    __syncthreads();

#pragma unroll
    for (int g = 0; g < 4; ++g) {
        const int id = g * 64 + lane;
        const int hh = id >> 5, jj = id & 31;
        float val = s_sc[wv][hh][jj];
        float mx = val;
        mx = fmaxf(mx, __shfl_xor(mx, 16, 32));
        mx = fmaxf(mx, __shfl_xor(mx, 8, 32));
        mx = fmaxf(mx, __shfl_xor(mx, 4, 32));
        mx = fmaxf(mx, __shfl_xor(mx, 2, 32));
        mx = fmaxf(mx, __shfl_xor(mx, 1, 32));
        float e = __expf(val - mx);
        float s = e;
        s += __shfl_xor(s, 16, 32);
        s += __shfl_xor(s, 8, 32);
        s += __shfl_xor(s, 4, 32);
        s += __shfl_xor(s, 2, 32);
        s += __shfl_xor(s, 1, 32);
        __builtin_nontemporal_store((_Float16)(e / s), wbuf + base + id);
    }
}

// ---------------- Attention pass 2: PV gather (32-deep MLP) ----------------
__global__ __launch_bounds__(256) void attn_pv(
    const _Float16* __restrict__ V, const _Float16* __restrict__ wbuf,
    const int* __restrict__ edges, _Float16* __restrict__ feat)
{
    __shared__ float s_w[4][HEADS][33];
    __shared__ int s_idx[4][KNB];
    const int t = threadIdx.x;
    const int wv = t >> 6;
    const int lane = t & 63;
    const int b = blockIdx.y;
    const int n = (blockIdx.x << 2) + wv;
    const int h = lane >> 3;
    const size_t nb = (size_t)b * NN;
    const size_t base = (nb + n) * COUT;
    const int c = lane * 4;

    if (lane < KNB) s_idx[wv][lane] = __builtin_nontemporal_load(edges + (nb + n) * KNB + lane);
    {
        const h4 wh = __builtin_nontemporal_load((const h4*)(wbuf + base + c));
        const int hh = lane >> 3;
        const int jj = (lane * 4) & 31;
        s_w[wv][hh][jj + 0] = (float)wh[0];
        s_w[wv][hh][jj + 1] = (float)wh[1];
        s_w[wv][hh][jj + 2] = (float)wh[2];
        s_w[wv][hh][jj + 3] = (float)wh[3];
    }
    __syncthreads();

    const _Float16* __restrict__ Vp = V + nb * COUT;
    h4 vreg[KNB];
#pragma unroll
    for (int j = 0; j < KNB; ++j)
        vreg[j] = *(const h4*)(Vp + (size_t)s_idx[wv][j] * COUT + c);

    float ax = 0.f, ay = 0.f, az = 0.f, aw = 0.f;
#pragma unroll
    for (int j = 0; j < KNB; ++j) {
        const float w = s_w[wv][h][j];
        ax += w * (float)vreg[j][0]; ay += w * (float)vreg[j][1];
        az += w * (float)vreg[j][2]; aw += w * (float)vreg[j][3];
    }
    h4 f; f[0] = (_Float16)ax; f[1] = (_Float16)ay; f[2] = (_Float16)az; f[3] = (_Float16)aw;
    __builtin_nontemporal_store(f, (h4*)(feat + base + c));  // feat aliases Q
}

// ---------------- Wo GEMM (fp16 MFMA) + fused BN partial sums ----------------
__global__ __launch_bounds__(256) void wo_kernel(
    const _Float16* __restrict__ feat, const float* __restrict__ Wo, float* __restrict__ o,
    float* __restrict__ ps, float* __restrict__ pss)
{
    __shared__ _Float16 wl[16][65][8];
    __shared__ _Float16 fl[16][65][8];
    const int t = threadIdx.x;
    const int i = blockIdx.x;
    const int xcd = i & 7;
    const int local = i >> 3;
    const int co0 = (local & 3) << 6;
    const int tl = local >> 2;
    const int g = tl * 8 + xcd;
    const int b = g >> 7;
    const int n0 = (g & 127) << 6;
    const int w = t >> 6, lane = t & 63;
    const int m = lane & 15, ko = lane >> 4;
    f4 acc[4];
#pragma unroll
    for (int j = 0; j < 4; ++j) acc[j] = (f4){0.f, 0.f, 0.f, 0.f};

    for (int c0 = 0; c0 < COUT; c0 += 128) {
#pragma unroll
        for (int it = 0; it < 8; ++it) {
            const int flat = t + it * 256;
            const int co = flat >> 5;
            const int k4 = (flat & 31) << 2;
            float4 wv = *(const float4*)(Wo + (size_t)(co0 + co) * COUT + c0 + k4);
            h4 hv; hv[0] = (_Float16)wv.x; hv[1] = (_Float16)wv.y;
            hv[2] = (_Float16)wv.z; hv[3] = (_Float16)wv.w;
            *(h4*)&wl[k4 >> 3][co][k4 & 7] = hv;
        }
#pragma unroll
        for (int it = 0; it < 4; ++it) {
            const int flat = t + it * 256;
            const int n = flat >> 4;
            const int c8 = flat & 15;
            const h8 fv = *(const h8*)(feat + ((size_t)b * NN + n0 + n) * COUT + c0 + c8 * 8);
            *(h8*)&fl[c8][n][0] = fv;
        }
        __syncthreads();
#pragma unroll
        for (int s = 0; s < 4; ++s) {
            const h8 a = *(const h8*)&wl[s * 4 + ko][w * 16 + m][0];
#pragma unroll
            for (int j = 0; j < 4; ++j) {
                const h8 bb = *(const h8*)&fl[s * 4 + ko][j * 16 + m][0];
                acc[j] = __builtin_amdgcn_mfma_f32_16x16x32_f16(a, bb, acc[j], 0, 0, 0);
            }
        }
        __syncthreads();
    }

    const int cob = co0 + w * 16 + ko * 4;
#pragma unroll
    for (int j = 0; j < 4; ++j) {
        const int n = n0 + j * 16 + m;
        *(f4*)(o + ((size_t)b * NN + n) * COUT + cob) = acc[j];
    }

    float s_[4], ss_[4];
#pragma unroll
    for (int r = 0; r < 4; ++r) {
        float sv = acc[0][r] + acc[1][r] + acc[2][r] + acc[3][r];
        float qv = acc[0][r] * acc[0][r] + acc[1][r] * acc[1][r]
                 + acc[2][r] * acc[2][r] + acc[3][r] * acc[3][r];
#pragma unroll
        for (int d = 1; d < 16; d <<= 1) {
            sv += __shfl_xor(sv, d, 16);
            qv += __shfl_xor(qv, d, 16);
        }
        s_[r] = sv; ss_[r] = qv;
    }
    if (m == 0) {
#pragma unroll
        for (int r = 0; r < 4; ++r) {
            atomicAdd(&ps[cob + r], s_[r]);
            atomicAdd(&pss[cob + r], ss_[r]);
        }
    }
}

// ---------------- BN apply + LeakyReLU + transpose to [b][co][n] ----------------
__global__ __launch_bounds__(256) void bn_apply(const float* __restrict__ o,
    const float* __restrict__ ps, const float* __restrict__ pss,
    const float* __restrict__ gamma, const float* __restrict__ beta,
    float* __restrict__ out)
{
    __shared__ float tile[64][68];
    __shared__ float s_sc[64], s_sh[64];
    const int i = blockIdx.x;
    const int nt_ = i & 127, ct = (i >> 7) & 3, b = i >> 9;
    const int n0 = nt_ << 6, co0 = ct << 6;
    const int t = threadIdx.x;
    if (t < 64) {
        const int co = co0 + t;
        const float inv = 1.f / (float)(BB * NN);
        const float mean = ps[co] * inv;
        const float var = pss[co] * inv - mean * mean;
        const float istd = rsqrtf(var + EPSV);
        const float sc = gamma[co] * istd;
        s_sc[t] = sc;
        s_sh[t] = beta[co] - mean * sc;
    }
    const int cq = (t & 15) << 2, rg = t >> 4;
#pragma unroll
    for (int it = 0; it < 4; ++it) {
        const int n = rg + it * 16;
        f4 v = *(const f4*)(o + ((size_t)b * NN + n0 + n) * COUT + co0 + cq);
        *(f4*)&tile[n][cq] = v;
    }
    __syncthreads();
    const int n4 = (t & 15) << 2, cg = t >> 4;
#pragma unroll
    for (int it = 0; it < 4; ++it) {
        const int co = cg + it * 16;
        const float sc = s_sc[co];
        const float sh = s_sh[co];
        f4 r;
#pragma unroll
        for (int j = 0; j < 4; ++j) {
            float v = sc * tile[n4 + j][co] + sh;
            r[j] = (v >= 0.f) ? v : SLOPE * v;
        }
        *(f4*)(out + ((size_t)b * COUT + co0 + co) * NN + n0 + n4) = r;
    }
}

extern "C" void kernel_launch(void* const* d_in, const int* in_sizes, int n_in,
                              void* d_out, int out_size, void* d_ws, size_t ws_size,
                              hipStream_t stream)
{
    const float* x     = (const float*)d_in[0];
    const int*   edges = (const int*)d_in[1];
    const float* Wq    = (const float*)d_in[2];
    const float* Wk    = (const float*)d_in[3];
    const float* Wv    = (const float*)d_in[4];
    const float* Wo    = (const float*)d_in[5];
    const float* gamma = (const float*)d_in[6];
    const float* beta  = (const float*)d_in[7];
    float* out = (float*)d_out;

    const size_t SZ = (size_t)BB * NN * COUT;      // 8,388,608 elements
    _Float16* Q    = (_Float16*)d_ws;
    _Float16* K    = Q + SZ;
    _Float16* V    = K + SZ;
    _Float16* wbuf = V + SZ;
    float*    o    = (float*)(wbuf + SZ);
    float*    ps   = o + SZ;
    float*    pss  = ps + COUT;
    _Float16* feat = Q;                            // alias: per-node exclusive

    qkv_kernel<<<dim3(12 * 128 * BB), 256, 0, stream>>>(x, Wq, Wk, Wv, Q, K, V, ps);
    attn_scores<<<dim3(NN / 4, BB), 256, 0, stream>>>(Q, K, edges, wbuf);
    attn_pv<<<dim3(NN / 4, BB), 256, 0, stream>>>(V, wbuf, edges, feat);
    wo_kernel<<<dim3(4 * 128 * BB), 256, 0, stream>>>(feat, Wo, o, ps, pss);
    bn_apply<<<dim3(2048), 256, 0, stream>>>(o, ps, pss, gamma, beta, out);
}